// Round 1
// baseline (300.414 us; speedup 1.0000x reference)
//
#include <hip/hip_runtime.h>

typedef unsigned short u16;
typedef unsigned int u32;
typedef __bf16 bf16x8 __attribute__((ext_vector_type(8)));
typedef float f32x4 __attribute__((ext_vector_type(4)));

// ---------- helpers ----------

__device__ __forceinline__ u16 f2bf(float f) {  // round-to-nearest-even fp32->bf16
  u32 u = __builtin_bit_cast(u32, f);
  u32 r = (u + 0x7fffu + ((u >> 16) & 1u)) >> 16;
  return (u16)r;
}
__device__ __forceinline__ u32 pk2(float a, float b) {
  return (u32)f2bf(a) | ((u32)f2bf(b) << 16);
}
__device__ __forceinline__ f32x4 mfma16(bf16x8 a, bf16x8 b, f32x4 c) {
  return __builtin_amdgcn_mfma_f32_16x16x32_bf16(a, b, c, 0, 0, 0);
}
// async global->LDS, 16B/lane; LDS dest = wave-uniform base + lane*16
__device__ __forceinline__ void glds16(const void* g, void* l) {
  typedef __attribute__((address_space(1))) void as1_void;
  typedef __attribute__((address_space(3))) void as3_void;
  __builtin_amdgcn_global_load_lds((as1_void*)g, (as3_void*)l, 16, 0, 0);
}

// ---------- kernel 1: fused prep ----------
// blocks [0,8192): x fp32->bf16 | [8192,8960): Wqkv^T | [8960,9216): Wproj^T
// [9216,9344): bias -> S^T D-layout table pre-scaled by log2(e)

__device__ __forceinline__ void transpose_body(const float* __restrict__ in,
                                               u16* __restrict__ out,
                                               int N, int n0, int k0) {
  __shared__ float t[32][33];
  int tx = threadIdx.x & 31, ty = threadIdx.x >> 5;  // 8 rows per pass
#pragma unroll
  for (int s = 0; s < 32; s += 8)
    t[ty + s][tx] = in[(long)(k0 + ty + s) * N + n0 + tx];
  __syncthreads();
#pragma unroll
  for (int s = 0; s < 32; s += 8)
    out[(long)(n0 + ty + s) * 512 + k0 + tx] = f2bf(t[tx][ty + s]);
}

__launch_bounds__(256)
__global__ void prep_k(const float* __restrict__ x, u16* __restrict__ xbf,
                       const float* __restrict__ Wqkv, u16* __restrict__ wqkvT,
                       const float* __restrict__ Wproj, u16* __restrict__ wprojT,
                       const float* __restrict__ bias, float* __restrict__ biasT) {
  const int id = blockIdx.x;
  if (id < 8192) {
    long i = ((long)id * 256 + threadIdx.x) * 8;
    float4 f0 = *(const float4*)(x + i);
    float4 f1 = *(const float4*)(x + i + 4);
    uint4 o;
    o.x = pk2(f0.x, f0.y);
    o.y = pk2(f0.z, f0.w);
    o.z = pk2(f1.x, f1.y);
    o.w = pk2(f1.z, f1.w);
    *(uint4*)(xbf + i) = o;
  } else if (id < 8960) {
    int bx = id - 8192;  // 768 = 48 x 16
    transpose_body(Wqkv, wqkvT, 1536, (bx % 48) * 32, (bx / 48) * 32);
  } else if (id < 9216) {
    int bx = id - 8960;  // 256 = 16 x 16
    transpose_body(Wproj, wprojT, 512, (bx & 15) * 32, (bx >> 4) * 32);
  } else {
    int hb = id - 9216;  // h*16 + rt
    int h = hb >> 4, rt = hb & 15;
    int lane = threadIdx.x & 63;
    int quad = lane >> 4, l15 = lane & 15;
    int jtg = threadIdx.x >> 6;  // 0..3
    const float L = 1.44269504f;
#pragma unroll
    for (int i = 0; i < 4; ++i) {
      int jt = jtg * 4 + i;
      float4 v = *(const float4*)&bias[((long)h * 256 + rt * 16 + l15) * 256 + jt * 16 + quad * 4];
      v.x *= L; v.y *= L; v.z *= L; v.w *= L;
      *(float4*)&biasT[(((long)hb * 16 + jt) * 64 + lane) * 4] = v;
    }
  }
}

// ---------- GEMM body: C = A(bf16 [M][512]) * Bt(bf16 [N][512])^T + bias ----------
// 256x256 tile, BK=64, 8 waves (2M x 4N), per-wave 128x64 output (acc[8][4]).
// Deep pipeline (T3+T4+T5): 4 phases per K-tile, raw s_barrier, counted vmcnt(4)
// at the tile boundary only (never 0 in the main loop), setprio(1) around MFMA.
// LDS: double-buffered chunk-major [c][row 256][32] with XOR swizzle
// (pos = g ^ ((row>>1)&3)) -> measured 0 bank conflicts. 128 KiB, 1 block/CU.
// Staging rotation (hazard-checked):
//   phase 0: stage (t+1) A-half0 -> other buffer   (that buffer done since tile t-1)
//   phase 1: stage (t+1) A-half1 -> other buffer
//   phase 2: stage (t+2) B-half0 -> this buffer    (B fully read by end of phase 1)
//   phase 3: stage (t+2) B-half1 -> this buffer
//   boundary: vmcnt(4) retires everything except the two newest B-half stages,
//   so tile t+1 is fully landed and in-flight writes only target finished regions.
// EPI=0: q/k cols -> natural [32768][1024] bf16; v cols -> v^T [(b*8+h)*64+d][8192] bf16.
// EPI=1: fp32 row-major [32768][512] output (d_out).

template <int EPI>
__device__ __forceinline__ void gemm_body(const u16* __restrict__ A, const u16* __restrict__ Bt,
                                          const float* __restrict__ bias,
                                          u16* __restrict__ oqk, u16* __restrict__ ovt,
                                          float* __restrict__ ofp,
                                          long arow0, long brow0) {
  constexpr int K = 512;
  constexpr int NT = 8;                 // K-tiles of 64
  __shared__ u16 Asm[2][16384];         // [buf][c*8192 + row*32 + g*8]  2x32KB
  __shared__ u16 Bsm[2][16384];

  const int tid = threadIdx.x;
  const int wave = tid >> 6, lane = tid & 63;
  const int quad = lane >> 4, l15 = lane & 15;
  const int wm = wave >> 2, wn = wave & 3;
  const int gsw = quad ^ ((l15 >> 1) & 3);

  // staging decomposition: thread handles 16B block f = ld*512 + tid
  //   c = ld, row-in-half = tid>>2, lds group = tid&3, global group = swizzled
  const int srow = tid >> 2;            // 0..127
  const int sg = (tid & 3) ^ ((srow >> 1) & 3);

  auto stA = [&](int buf, int t, int mh) {
#pragma unroll
    for (int ld = 0; ld < 2; ++ld)
      glds16(A + (arow0 + mh * 128 + srow) * K + t * 64 + ld * 32 + sg * 8,
             &Asm[buf][(ld * 1024 + mh * 512 + wave * 64) * 8]);
  };
  auto stB = [&](int buf, int t, int mh) {
#pragma unroll
    for (int ld = 0; ld < 2; ++ld)
      glds16(Bt + (brow0 + mh * 128 + srow) * K + t * 64 + ld * 32 + sg * 8,
             &Bsm[buf][(ld * 1024 + mh * 512 + wave * 64) * 8]);
  };

  f32x4 acc[8][4] = {};
  bf16x8 aA[2][4], b0[2][2], b1[2][2];

  // prologue: tile0 complete + tile1's B halves; wait tile0 (leave 2 halves in flight)
  stA(0, 0, 0); stA(0, 0, 1); stB(0, 0, 0); stB(0, 0, 1);
  stB(1, 1, 0); stB(1, 1, 1);
  asm volatile("s_waitcnt vmcnt(4)" ::: "memory");
  __builtin_amdgcn_s_barrier();

#pragma unroll
  for (int t = 0; t < NT; ++t) {
    const int buf = t & 1;
    u16* As = Asm[buf];
    u16* Bs = Bsm[buf];

    // ---- phase 0: read A(qm0) 8 + B(qn0) 4; stage (t+1) A-half0 ----
#pragma unroll
    for (int c = 0; c < 2; ++c) {
#pragma unroll
      for (int i = 0; i < 4; ++i)
        aA[c][i] = *(const bf16x8*)&As[(c * 256 + wm * 128 + i * 16 + l15) * 32 + gsw * 8];
#pragma unroll
      for (int j = 0; j < 2; ++j)
        b0[c][j] = *(const bf16x8*)&Bs[(c * 256 + wn * 64 + j * 16 + l15) * 32 + gsw * 8];
    }
    if (t + 1 < NT) stA(buf ^ 1, t + 1, 0);
    __builtin_amdgcn_s_barrier();
    asm volatile("s_waitcnt lgkmcnt(0)" ::: "memory");
    __builtin_amdgcn_s_setprio(1);
#pragma unroll
    for (int c = 0; c < 2; ++c)
#pragma unroll
      for (int i = 0; i < 4; ++i)
#pragma unroll
        for (int j = 0; j < 2; ++j)
          acc[i][j] = mfma16(aA[c][i], b0[c][j], acc[i][j]);
    __builtin_amdgcn_s_setprio(0);
    __builtin_amdgcn_s_barrier();

    // ---- phase 1: read B(qn1) 4; stage (t+1) A-half1 ----
#pragma unroll
    for (int c = 0; c < 2; ++c)
#pragma unroll
      for (int j = 0; j < 2; ++j)
        b1[c][j] = *(const bf16x8*)&Bs[(c * 256 + wn * 64 + (2 + j) * 16 + l15) * 32 + gsw * 8];
    if (t + 1 < NT) stA(buf ^ 1, t + 1, 1);
    __builtin_amdgcn_s_barrier();
    asm volatile("s_waitcnt lgkmcnt(0)" ::: "memory");
    __builtin_amdgcn_s_setprio(1);
#pragma unroll
    for (int c = 0; c < 2; ++c)
#pragma unroll
      for (int i = 0; i < 4; ++i)
#pragma unroll
        for (int j = 0; j < 2; ++j)
          acc[i][2 + j] = mfma16(aA[c][i], b1[c][j], acc[i][2 + j]);
    __builtin_amdgcn_s_setprio(0);
    __builtin_amdgcn_s_barrier();

    // ---- phase 2: read A(qm1) 8; stage (t+2) B-half0 ----
#pragma unroll
    for (int c = 0; c < 2; ++c)
#pragma unroll
      for (int i = 0; i < 4; ++i)
        aA[c][i] = *(const bf16x8*)&As[(c * 256 + wm * 128 + (4 + i) * 16 + l15) * 32 + gsw * 8];
    if (t + 2 < NT) stB(buf, t + 2, 0);
    __builtin_amdgcn_s_barrier();
    asm volatile("s_waitcnt lgkmcnt(0)" ::: "memory");
    __builtin_amdgcn_s_setprio(1);
#pragma unroll
    for (int c = 0; c < 2; ++c)
#pragma unroll
      for (int i = 0; i < 4; ++i)
#pragma unroll
        for (int j = 0; j < 2; ++j)
          acc[4 + i][j] = mfma16(aA[c][i], b0[c][j], acc[4 + i][j]);
    __builtin_amdgcn_s_setprio(0);
    __builtin_amdgcn_s_barrier();

    // ---- phase 3: stage (t+2) B-half1; boundary vmcnt ----
    if (t + 2 < NT) stB(buf, t + 2, 1);
    __builtin_amdgcn_s_barrier();
    __builtin_amdgcn_s_setprio(1);
#pragma unroll
    for (int c = 0; c < 2; ++c)
#pragma unroll
      for (int i = 0; i < 4; ++i)
#pragma unroll
        for (int j = 0; j < 2; ++j)
          acc[4 + i][2 + j] = mfma16(aA[c][i], b1[c][j], acc[4 + i][2 + j]);
    __builtin_amdgcn_s_setprio(0);
    if (t < NT - 2)
      asm volatile("s_waitcnt vmcnt(4)" ::: "memory");
    else if (t == NT - 2)
      asm volatile("s_waitcnt vmcnt(0)" ::: "memory");
    if (t < NT - 1) __builtin_amdgcn_s_barrier();
  }

  // epilogue: D-layout row = quad*4 + r, col = l15
#pragma unroll
  for (int j = 0; j < 4; ++j) {
    const int C = (int)brow0 + wn * 64 + j * 16 + l15;
    const float bc = bias[C];
#pragma unroll
    for (int i = 0; i < 8; ++i) {
      const long R0 = arow0 + wm * 128 + i * 16 + quad * 4;
      float v4[4];
#pragma unroll
      for (int r = 0; r < 4; ++r) v4[r] = acc[i][j][r] + bc;
      if constexpr (EPI == 0) {
        if (C < 1024) {  // q/k: natural rows (block-uniform branch)
#pragma unroll
          for (int r = 0; r < 4; ++r) oqk[(R0 + r) * 1024 + C] = f2bf(v4[r]);
        } else {         // v: transposed, packed 8B along n
          const int hc = (C >> 6) & 7, dc = C & 63;
          const int b = (int)(R0 >> 13), n0 = (int)(R0 & 8191);
          uint2 w;
          w.x = pk2(v4[0], v4[1]);
          w.y = pk2(v4[2], v4[3]);
          *(uint2*)&ovt[((long)(b * 8 + hc) * 64 + dc) * 8192 + n0] = w;
        }
      } else {
#pragma unroll
        for (int r = 0; r < 4; ++r) ofp[(R0 + r) * 512 + C] = v4[r];
      }
    }
  }
}

// XCD-aware swizzle (heuristic, perf-only): xcd = bid % 8 owns a contiguous band of
// 16 M-tiles; N fastest within the band -> each A-tile lives in exactly one XCD L2,
// B stays resident.

__launch_bounds__(512, 2)
__global__ void qkv_gemm_k(const u16* __restrict__ A, const u16* __restrict__ Bt,
                           const float* __restrict__ bias,
                           u16* __restrict__ oqk, u16* __restrict__ ovt) {
  int bid = blockIdx.x;               // 768 = 8 xcd * 16 mtl * 6 nt
  int xcd = bid & 7, i = bid >> 3;
  int nt = i % 6, mtl = i / 6;
  gemm_body<0>(A, Bt, bias, oqk, ovt, nullptr,
               (long)(xcd * 16 + mtl) * 256, (long)nt * 256);
}

__launch_bounds__(512, 2)
__global__ void proj_gemm_k(const u16* __restrict__ A, const u16* __restrict__ Bt,
                            const float* __restrict__ bias, float* __restrict__ ofp) {
  int bid = blockIdx.x;               // 256 = 8 xcd * 16 mtl * 2 nt
  int xcd = bid & 7, i = bid >> 3;
  int nt = i & 1, mtl = i >> 1;
  gemm_body<1>(A, Bt, bias, nullptr, nullptr, ofp,
               (long)(xcd * 16 + mtl) * 256, (long)nt * 256);
}

// ---------- attention: one 512-thread block per (b,h,window) ----------
// S^T = K Q^T formulation, streaming no-max softmax (scores bounded ~|2|).
// XCD swizzle clusters the 8 heads of a window on one XCD (q/k rows share lines).
// q frags hoisted above the barrier to overlap staging.

__launch_bounds__(512, 4)
__global__ void attn_win(const u16* __restrict__ qk, const u16* __restrict__ vtb,
                         const float* __restrict__ biasT, u16* __restrict__ og) {
  __shared__ __align__(16) u16 kS[16384];    // [c][256 t][32], pos = g^((t>>1)&3)   32 KB
  __shared__ __align__(16) u16 vS[16384];    // [kk 8][64 d][32], pos = g^((d>>1)&3) 32 KB
  __shared__ __align__(16) u16 pS[8][1024];  // per-wave 2 slots x [16 q][32 t]      16 KB

  const int tid = threadIdx.x;
  const int wave = tid >> 6, lane = tid & 63;
  const int quad = lane >> 4, l15 = lane & 15;
  const int gsw = quad ^ ((l15 >> 1) & 3);

  // swizzle: 1024 = 8 xcd * 8 h * 16 wl ; window = xcd*16 + wl  (all 8 heads co-XCD)
  const int wi = blockIdx.x;
  const int xcd = wi & 7, hi = (wi >> 3) & 7, wl = wi >> 6;
  const int win = xcd * 16 + wl;             // [0,128)
  const int nwi = win & 31, bi = win >> 5;
  const long grow = (long)bi * 8192 + nwi * 256;
  const u16* qp = qk + grow * 1024 + hi * 64;
  const u16* kp = qp + 512;
  const u16* vp = vtb + (long)(bi * 8 + hi) * 64 * 8192 + nwi * 256;  // [d][256]

  // q B-frags for both sub-chunks, issued before the barrier (overlap staging)
  bf16x8 bq[2][2];
#pragma unroll
  for (int sc = 0; sc < 2; ++sc) {
    const int q0 = wave * 32 + sc * 16;
    bq[sc][0] = *(const bf16x8*)&qp[(long)(q0 + l15) * 1024 + quad * 8];
    bq[sc][1] = *(const bf16x8*)&qp[(long)(q0 + l15) * 1024 + 32 + quad * 8];
  }

  // stage k rows -> chunk-major swizzled LDS (512 threads: 4 iters)
#pragma unroll
  for (int it = 0; it < 4; ++it) {
    int flat = it * 512 + tid;
    int t = flat >> 3, dg = flat & 7;
    int c = dg >> 2, gp = (dg & 3) ^ ((t >> 1) & 3);
    int4 val = *(const int4*)&kp[(long)t * 1024 + dg * 8];
    *(int4*)&kS[c * 8192 + t * 32 + gp * 8] = val;
  }
  // stage v^T rows -> chunk-major swizzled LDS (coalesced 512B/d-row)
#pragma unroll
  for (int it = 0; it < 4; ++it) {
    int flat = it * 512 + tid;
    int d = flat >> 5, tg = flat & 31;
    int kk = tg >> 2, gp = (tg & 3) ^ ((d >> 1) & 3);
    int4 val = *(const int4*)&vp[(long)d * 8192 + tg * 8];
    *(int4*)&vS[kk * 2048 + d * 32 + gp * 8] = val;
  }
  __syncthreads();

  u16* Pw = pS[wave];
  const float cscale = 0.18033688f;  // 64^-0.5 * log2(e)

#pragma unroll
  for (int sc = 0; sc < 2; ++sc) {
    const int q0 = wave * 32 + sc * 16;
    const int rt = wave * 2 + sc;
    const float* bT = &biasT[(long)(hi * 16 + rt) * 16 * 64 * 4];

    f32x4 sum4 = {0.f, 0.f, 0.f, 0.f};
    f32x4 o[4] = {};

#pragma unroll
    for (int m = 0; m < 4; ++m) {
      // S-stream: 4 jt -> exp2 -> P slots (kk = m*2, m*2+1)
#pragma unroll
      for (int j2 = 0; j2 < 4; ++j2) {
        const int jt = m * 4 + j2;
        bf16x8 a0 = *(const bf16x8*)&kS[(jt * 16 + l15) * 32 + gsw * 8];
        bf16x8 a1 = *(const bf16x8*)&kS[8192 + (jt * 16 + l15) * 32 + gsw * 8];
        f32x4 z = {0.f, 0.f, 0.f, 0.f};
        z = mfma16(a0, bq[sc][0], z);
        z = mfma16(a1, bq[sc][1], z);
        f32x4 bb = *(const f32x4*)&bT[(long)jt * 256 + lane * 4];
        f32x4 p;
#pragma unroll
        for (int r = 0; r < 4; ++r) {
          p[r] = __builtin_exp2f(z[r] * cscale + bb[r]);
          sum4[r] += p[r];
        }
        const int gp = ((jt & 1) * 2 + (quad >> 1)) ^ ((l15 >> 1) & 3);
        const int slot = (jt >> 1) & 1;
        uint2 w;
        w.x = pk2(p[0], p[1]);
        w.y = pk2(p[2], p[3]);
        *(uint2*)&Pw[slot * 512 + l15 * 32 + gp * 8 + (quad & 1) * 4] = w;
      }
      // PV for the 2 completed chunks (same-wave DS in-order; no barrier)
#pragma unroll
      for (int kk2 = 0; kk2 < 2; ++kk2) {
        const int kk = m * 2 + kk2;
        bf16x8 bp = *(const bf16x8*)&Pw[kk2 * 512 + l15 * 32 + gsw * 8];
#pragma unroll
        for (int dt = 0; dt < 4; ++dt) {
          bf16x8 av = *(const bf16x8*)&vS[kk * 2048 + (dt * 16 + l15) * 32 + gsw * 8];
          o[dt] = mfma16(av, bp, o[dt]);  // O^T[d][q]
        }
      }
    }

    // rowsum -> inv (q = l15 lives in-lane; 2 cross-quad shuffles)
    float sum = (sum4[0] + sum4[1]) + (sum4[2] + sum4[3]);
    sum += __shfl_xor(sum, 16);
    sum += __shfl_xor(sum, 32);
    const float inv = 1.0f / sum;

    // store: lane holds 4 consecutive d per dt at row n = grow+q0+l15 -> 8B packs
    const long rowoff = (grow + q0 + l15) * 512 + hi * 64 + quad * 4;
#pragma unroll
    for (int dt = 0; dt < 4; ++dt) {
      uint2 w;
      w.x = pk2(o[dt][0] * inv, o[dt][1] * inv);
      w.y = pk2(o[dt][2] * inv, o[dt][3] * inv);
      *(uint2*)&og[rowoff + dt * 16] = w;
    }
  }
}

// ---------- launcher ----------

extern "C" void kernel_launch(void* const* d_in, const int* in_sizes, int n_in,
                              void* d_out, int out_size, void* d_ws, size_t ws_size,
                              hipStream_t stream) {
  const float* x     = (const float*)d_in[0];
  const float* Wqkv  = (const float*)d_in[1];
  const float* bqkv  = (const float*)d_in[2];
  const float* Wproj = (const float*)d_in[3];
  const float* bproj = (const float*)d_in[4];
  const float* abias = (const float*)d_in[5];
  float* out = (float*)d_out;

  // workspace layout (bytes):
  //   qk natural bf16 [32768][1024]: 67,108,864
  //   v^T bf16 [2048][8192]:         33,554,432   (ends 100,663,296)
  //   WqkvT bf16: 1,572,864 | WprojT bf16: 524,288 | biasT fp32: 2,097,152
  //   x_bf16 [32768][512] (aliased as attn_out after qkv GEMM): 33,554,432
  char* ws = (char*)d_ws;
  u16*   qkp    = (u16*)(ws);
  u16*   vtb    = (u16*)(ws + 67108864L);
  u16*   wqkvT  = (u16*)(ws + 100663296L);
  u16*   wprojT = (u16*)(ws + 102236160L);
  float* biasTp = (float*)(ws + 102760448L);
  u16*   xbf    = (u16*)(ws + 104857600L);
  u16*   attnout = xbf;  // safe: x_bf16 dead after qkv GEMM (stream-ordered)

  prep_k<<<9344, 256, 0, stream>>>(x, xbf, Wqkv, wqkvT, Wproj, wprojT, abias, biasTp);
  qkv_gemm_k<<<768, 512, 0, stream>>>(xbf, wqkvT, bqkv, qkp, vtb);
  attn_win<<<1024, 512, 0, stream>>>(qkp, vtb, biasTp, attnout);
  proj_gemm_k<<<256, 512, 0, stream>>>(attnout, wprojT, bproj, out);
}

// Round 2
// 297.889 us; speedup vs baseline: 1.0085x; 1.0085x over previous
//
#include <hip/hip_runtime.h>

typedef unsigned short u16;
typedef unsigned int u32;
typedef __bf16 bf16x8 __attribute__((ext_vector_type(8)));
typedef float f32x4 __attribute__((ext_vector_type(4)));

// ---------- helpers ----------

__device__ __forceinline__ u16 f2bf(float f) {  // round-to-nearest-even fp32->bf16
  u32 u = __builtin_bit_cast(u32, f);
  u32 r = (u + 0x7fffu + ((u >> 16) & 1u)) >> 16;
  return (u16)r;
}
__device__ __forceinline__ u32 pk2(float a, float b) {
  return (u32)f2bf(a) | ((u32)f2bf(b) << 16);
}
__device__ __forceinline__ f32x4 mfma16(bf16x8 a, bf16x8 b, f32x4 c) {
  return __builtin_amdgcn_mfma_f32_16x16x32_bf16(a, b, c, 0, 0, 0);
}
// async global->LDS, 16B/lane; LDS dest = wave-uniform base + lane*16
__device__ __forceinline__ void glds16(const void* g, void* l) {
  typedef __attribute__((address_space(1))) void as1_void;
  typedef __attribute__((address_space(3))) void as3_void;
  __builtin_amdgcn_global_load_lds((as1_void*)g, (as3_void*)l, 16, 0, 0);
}

// ---------- kernel 1: fused prep ----------
// blocks [0,8192): x fp32->bf16 | [8192,8960): Wqkv^T | [8960,9216): Wproj^T
// [9216,9344): bias -> S^T D-layout table pre-scaled by log2(e)

__device__ __forceinline__ void transpose_body(const float* __restrict__ in,
                                               u16* __restrict__ out,
                                               int N, int n0, int k0) {
  __shared__ float t[32][33];
  int tx = threadIdx.x & 31, ty = threadIdx.x >> 5;  // 8 rows per pass
#pragma unroll
  for (int s = 0; s < 32; s += 8)
    t[ty + s][tx] = in[(long)(k0 + ty + s) * N + n0 + tx];
  __syncthreads();
#pragma unroll
  for (int s = 0; s < 32; s += 8)
    out[(long)(n0 + ty + s) * 512 + k0 + tx] = f2bf(t[tx][ty + s]);
}

__launch_bounds__(256)
__global__ void prep_k(const float* __restrict__ x, u16* __restrict__ xbf,
                       const float* __restrict__ Wqkv, u16* __restrict__ wqkvT,
                       const float* __restrict__ Wproj, u16* __restrict__ wprojT,
                       const float* __restrict__ bias, float* __restrict__ biasT) {
  const int id = blockIdx.x;
  if (id < 8192) {
    long i = ((long)id * 256 + threadIdx.x) * 8;
    float4 f0 = *(const float4*)(x + i);
    float4 f1 = *(const float4*)(x + i + 4);
    uint4 o;
    o.x = pk2(f0.x, f0.y);
    o.y = pk2(f0.z, f0.w);
    o.z = pk2(f1.x, f1.y);
    o.w = pk2(f1.z, f1.w);
    *(uint4*)(xbf + i) = o;
  } else if (id < 8960) {
    int bx = id - 8192;  // 768 = 48 x 16
    transpose_body(Wqkv, wqkvT, 1536, (bx % 48) * 32, (bx / 48) * 32);
  } else if (id < 9216) {
    int bx = id - 8960;  // 256 = 16 x 16
    transpose_body(Wproj, wprojT, 512, (bx & 15) * 32, (bx >> 4) * 32);
  } else {
    int hb = id - 9216;  // h*16 + rt
    int h = hb >> 4, rt = hb & 15;
    int lane = threadIdx.x & 63;
    int quad = lane >> 4, l15 = lane & 15;
    int jtg = threadIdx.x >> 6;  // 0..3
    const float L = 1.44269504f;
#pragma unroll
    for (int i = 0; i < 4; ++i) {
      int jt = jtg * 4 + i;
      float4 v = *(const float4*)&bias[((long)h * 256 + rt * 16 + l15) * 256 + jt * 16 + quad * 4];
      v.x *= L; v.y *= L; v.z *= L; v.w *= L;
      *(float4*)&biasT[(((long)hb * 16 + jt) * 64 + lane) * 4] = v;
    }
  }
}

// ---------- GEMM body: C = A(bf16 [M][512]) * Bt(bf16 [N][512])^T + bias ----------
// 256x256 tile, BK=64, 8 waves (2M x 4N), per-wave 128x64 output (acc[8][4]).
// 4 phases per K-tile, raw s_barrier, counted vmcnt(8) at the tile boundary only,
// setprio(1) around MFMA, sched_barrier(0) after each lgkmcnt(0) (rule #18).
//
// Staging rotation DERIVED from read-completion points (round-1 post-mortem: A was
// staged only ~2 phases before its vmcnt -> exposed ~900cy HBM latency per tile):
//   B[buf] reads (b0 ph0, b1 ph1) all complete at ph1-end barrier -> stage B(t+2) in ph2
//   A[buf] reads (lo ph0, hi ph2) all complete at ph2-end barrier -> stage A(t+2) in ph3
//   boundary vmcnt(8): retires tile t+1's 8 loads (issued ph2/ph3 of tile t-1, i.e.
//   4-5 phases earlier ~ >=1000cy of work -> HBM latency covered), keeps t+2 in flight.
// Prologue: tiles 0+1 fully staged (16 loads), vmcnt(8) lands tile 0.
// Tail: t==NT-2 -> vmcnt(0); t==NT-1 -> no wait.
//
// LDS: double-buffered chunk-major [c][row 256][32] with XOR swizzle
// (pos = g ^ ((row>>1)&3)) -> measured 0 bank conflicts. 128 KiB, 1 block/CU.
// EPI=0: q/k cols -> natural [32768][1024] bf16; v cols -> v^T [(b*8+h)*64+d][8192] bf16.
// EPI=1: fp32 row-major [32768][512] output (d_out).

template <int EPI>
__device__ __forceinline__ void gemm_body(const u16* __restrict__ A, const u16* __restrict__ Bt,
                                          const float* __restrict__ bias,
                                          u16* __restrict__ oqk, u16* __restrict__ ovt,
                                          float* __restrict__ ofp,
                                          long arow0, long brow0) {
  constexpr int K = 512;
  constexpr int NT = 8;                 // K-tiles of 64
  __shared__ u16 Asm[2][16384];         // [buf][c*8192 + row*32 + g*8]  2x32KB
  __shared__ u16 Bsm[2][16384];

  const int tid = threadIdx.x;
  const int wave = tid >> 6, lane = tid & 63;
  const int quad = lane >> 4, l15 = lane & 15;
  const int wm = wave >> 2, wn = wave & 3;
  const int gsw = quad ^ ((l15 >> 1) & 3);

  // staging decomposition: thread handles 16B block f = ld*512 + tid
  //   c = ld, row-in-half = tid>>2, lds group = tid&3, global group = swizzled
  const int srow = tid >> 2;            // 0..127
  const int sg = (tid & 3) ^ ((srow >> 1) & 3);

  auto stA = [&](int t) {               // full A tile (4 loads/thread) -> Asm[t&1]
#pragma unroll
    for (int mh = 0; mh < 2; ++mh)
#pragma unroll
      for (int ld = 0; ld < 2; ++ld)
        glds16(A + (arow0 + mh * 128 + srow) * K + t * 64 + ld * 32 + sg * 8,
               &Asm[t & 1][(ld * 1024 + mh * 512 + wave * 64) * 8]);
  };
  auto stB = [&](int t) {               // full B tile (4 loads/thread) -> Bsm[t&1]
#pragma unroll
    for (int mh = 0; mh < 2; ++mh)
#pragma unroll
      for (int ld = 0; ld < 2; ++ld)
        glds16(Bt + (brow0 + mh * 128 + srow) * K + t * 64 + ld * 32 + sg * 8,
               &Bsm[t & 1][(ld * 1024 + mh * 512 + wave * 64) * 8]);
  };

  f32x4 acc[8][4] = {};
  bf16x8 aA[2][4], b0[2][2], b1[2][2];

  // prologue: tiles 0 and 1 fully staged; wait tile 0 (tile 1's 8 loads in flight)
  stA(0); stB(0); stA(1); stB(1);
  asm volatile("s_waitcnt vmcnt(8)" ::: "memory");
  __builtin_amdgcn_s_barrier();

#pragma unroll
  for (int t = 0; t < NT; ++t) {
    u16* As = Asm[t & 1];
    u16* Bs = Bsm[t & 1];

    // ---- phase 0: read A-lo (8) + b0 (4); MFMA acc[0..3][0..1] ----
#pragma unroll
    for (int c = 0; c < 2; ++c) {
#pragma unroll
      for (int i = 0; i < 4; ++i)
        aA[c][i] = *(const bf16x8*)&As[(c * 256 + wm * 128 + i * 16 + l15) * 32 + gsw * 8];
#pragma unroll
      for (int j = 0; j < 2; ++j)
        b0[c][j] = *(const bf16x8*)&Bs[(c * 256 + wn * 64 + j * 16 + l15) * 32 + gsw * 8];
    }
    __builtin_amdgcn_s_barrier();
    asm volatile("s_waitcnt lgkmcnt(0)" ::: "memory");
    __builtin_amdgcn_sched_barrier(0);
    __builtin_amdgcn_s_setprio(1);
#pragma unroll
    for (int c = 0; c < 2; ++c)
#pragma unroll
      for (int i = 0; i < 4; ++i)
#pragma unroll
        for (int j = 0; j < 2; ++j)
          acc[i][j] = mfma16(aA[c][i], b0[c][j], acc[i][j]);
    __builtin_amdgcn_s_setprio(0);
    __builtin_amdgcn_s_barrier();

    // ---- phase 1: read b1 (4); MFMA acc[0..3][2..3] ----
#pragma unroll
    for (int c = 0; c < 2; ++c)
#pragma unroll
      for (int j = 0; j < 2; ++j)
        b1[c][j] = *(const bf16x8*)&Bs[(c * 256 + wn * 64 + (2 + j) * 16 + l15) * 32 + gsw * 8];
    __builtin_amdgcn_s_barrier();
    asm volatile("s_waitcnt lgkmcnt(0)" ::: "memory");
    __builtin_amdgcn_sched_barrier(0);
    __builtin_amdgcn_s_setprio(1);
#pragma unroll
    for (int c = 0; c < 2; ++c)
#pragma unroll
      for (int i = 0; i < 4; ++i)
#pragma unroll
        for (int j = 0; j < 2; ++j)
          acc[i][2 + j] = mfma16(aA[c][i], b1[c][j], acc[i][2 + j]);
    __builtin_amdgcn_s_setprio(0);
    __builtin_amdgcn_s_barrier();
    // all B[buf] reads complete here (b0 ph0, b1 ph1)

    // ---- phase 2: read A-hi (8); stage B(t+2); MFMA acc[4..7][0..1] ----
#pragma unroll
    for (int c = 0; c < 2; ++c)
#pragma unroll
      for (int i = 0; i < 4; ++i)
        aA[c][i] = *(const bf16x8*)&As[(c * 256 + wm * 128 + (4 + i) * 16 + l15) * 32 + gsw * 8];
    if (t + 2 < NT) stB(t + 2);
    __builtin_amdgcn_s_barrier();
    asm volatile("s_waitcnt lgkmcnt(0)" ::: "memory");
    __builtin_amdgcn_sched_barrier(0);
    __builtin_amdgcn_s_setprio(1);
#pragma unroll
    for (int c = 0; c < 2; ++c)
#pragma unroll
      for (int i = 0; i < 4; ++i)
#pragma unroll
        for (int j = 0; j < 2; ++j)
          acc[4 + i][j] = mfma16(aA[c][i], b0[c][j], acc[4 + i][j]);
    __builtin_amdgcn_s_setprio(0);
    __builtin_amdgcn_s_barrier();
    // all A[buf] reads complete here (lo ph0, hi ph2)

    // ---- phase 3: stage A(t+2); MFMA acc[4..7][2..3]; boundary vmcnt ----
    if (t + 2 < NT) stA(t + 2);
    __builtin_amdgcn_s_barrier();
    __builtin_amdgcn_s_setprio(1);
#pragma unroll
    for (int c = 0; c < 2; ++c)
#pragma unroll
      for (int i = 0; i < 4; ++i)
#pragma unroll
        for (int j = 0; j < 2; ++j)
          acc[4 + i][2 + j] = mfma16(aA[c][i], b1[c][j], acc[4 + i][2 + j]);
    __builtin_amdgcn_s_setprio(0);
    if (t < NT - 2)
      asm volatile("s_waitcnt vmcnt(8)" ::: "memory");   // tile t+1 landed, t+2 in flight
    else if (t == NT - 2)
      asm volatile("s_waitcnt vmcnt(0)" ::: "memory");   // tile NT-1 landed
    if (t < NT - 1) __builtin_amdgcn_s_barrier();
  }

  // epilogue: D-layout row = quad*4 + r, col = l15
#pragma unroll
  for (int j = 0; j < 4; ++j) {
    const int C = (int)brow0 + wn * 64 + j * 16 + l15;
    const float bc = bias[C];
#pragma unroll
    for (int i = 0; i < 8; ++i) {
      const long R0 = arow0 + wm * 128 + i * 16 + quad * 4;
      float v4[4];
#pragma unroll
      for (int r = 0; r < 4; ++r) v4[r] = acc[i][j][r] + bc;
      if constexpr (EPI == 0) {
        if (C < 1024) {  // q/k: natural rows (block-uniform branch)
#pragma unroll
          for (int r = 0; r < 4; ++r) oqk[(R0 + r) * 1024 + C] = f2bf(v4[r]);
        } else {         // v: transposed, packed 8B along n
          const int hc = (C >> 6) & 7, dc = C & 63;
          const int b = (int)(R0 >> 13), n0 = (int)(R0 & 8191);
          uint2 w;
          w.x = pk2(v4[0], v4[1]);
          w.y = pk2(v4[2], v4[3]);
          *(uint2*)&ovt[((long)(b * 8 + hc) * 64 + dc) * 8192 + n0] = w;
        }
      } else {
#pragma unroll
        for (int r = 0; r < 4; ++r) ofp[(R0 + r) * 512 + C] = v4[r];
      }
    }
  }
}

// XCD-aware swizzle (heuristic, perf-only): xcd = bid % 8 owns a contiguous band of
// 16 M-tiles; N fastest within the band -> each A-tile lives in exactly one XCD L2,
// B stays resident.

__launch_bounds__(512, 2)
__global__ void qkv_gemm_k(const u16* __restrict__ A, const u16* __restrict__ Bt,
                           const float* __restrict__ bias,
                           u16* __restrict__ oqk, u16* __restrict__ ovt) {
  int bid = blockIdx.x;               // 768 = 8 xcd * 16 mtl * 6 nt
  int xcd = bid & 7, i = bid >> 3;
  int nt = i % 6, mtl = i / 6;
  gemm_body<0>(A, Bt, bias, oqk, ovt, nullptr,
               (long)(xcd * 16 + mtl) * 256, (long)nt * 256);
}

__launch_bounds__(512, 2)
__global__ void proj_gemm_k(const u16* __restrict__ A, const u16* __restrict__ Bt,
                            const float* __restrict__ bias, float* __restrict__ ofp) {
  int bid = blockIdx.x;               // 256 = 8 xcd * 16 mtl * 2 nt
  int xcd = bid & 7, i = bid >> 3;
  int nt = i & 1, mtl = i >> 1;
  gemm_body<1>(A, Bt, bias, nullptr, nullptr, ofp,
               (long)(xcd * 16 + mtl) * 256, (long)nt * 256);
}

// ---------- attention: one 512-thread block per (b,h,window) ----------
// S^T = K Q^T formulation, streaming no-max softmax (scores bounded ~|2|).
// XCD swizzle clusters the 8 heads of a window on one XCD (q/k rows share lines).
// q frags hoisted above the barrier to overlap staging.

__launch_bounds__(512, 4)
__global__ void attn_win(const u16* __restrict__ qk, const u16* __restrict__ vtb,
                         const float* __restrict__ biasT, u16* __restrict__ og) {
  __shared__ __align__(16) u16 kS[16384];    // [c][256 t][32], pos = g^((t>>1)&3)   32 KB
  __shared__ __align__(16) u16 vS[16384];    // [kk 8][64 d][32], pos = g^((d>>1)&3) 32 KB
  __shared__ __align__(16) u16 pS[8][1024];  // per-wave 2 slots x [16 q][32 t]      16 KB

  const int tid = threadIdx.x;
  const int wave = tid >> 6, lane = tid & 63;
  const int quad = lane >> 4, l15 = lane & 15;
  const int gsw = quad ^ ((l15 >> 1) & 3);

  // swizzle: 1024 = 8 xcd * 8 h * 16 wl ; window = xcd*16 + wl  (all 8 heads co-XCD)
  const int wi = blockIdx.x;
  const int xcd = wi & 7, hi = (wi >> 3) & 7, wl = wi >> 6;
  const int win = xcd * 16 + wl;             // [0,128)
  const int nwi = win & 31, bi = win >> 5;
  const long grow = (long)bi * 8192 + nwi * 256;
  const u16* qp = qk + grow * 1024 + hi * 64;
  const u16* kp = qp + 512;
  const u16* vp = vtb + (long)(bi * 8 + hi) * 64 * 8192 + nwi * 256;  // [d][256]

  // q B-frags for both sub-chunks, issued before the barrier (overlap staging)
  bf16x8 bq[2][2];
#pragma unroll
  for (int sc = 0; sc < 2; ++sc) {
    const int q0 = wave * 32 + sc * 16;
    bq[sc][0] = *(const bf16x8*)&qp[(long)(q0 + l15) * 1024 + quad * 8];
    bq[sc][1] = *(const bf16x8*)&qp[(long)(q0 + l15) * 1024 + 32 + quad * 8];
  }

  // stage k rows -> chunk-major swizzled LDS (512 threads: 4 iters)
#pragma unroll
  for (int it = 0; it < 4; ++it) {
    int flat = it * 512 + tid;
    int t = flat >> 3, dg = flat & 7;
    int c = dg >> 2, gp = (dg & 3) ^ ((t >> 1) & 3);
    int4 val = *(const int4*)&kp[(long)t * 1024 + dg * 8];
    *(int4*)&kS[c * 8192 + t * 32 + gp * 8] = val;
  }
  // stage v^T rows -> chunk-major swizzled LDS (coalesced 512B/d-row)
#pragma unroll
  for (int it = 0; it < 4; ++it) {
    int flat = it * 512 + tid;
    int d = flat >> 5, tg = flat & 31;
    int kk = tg >> 2, gp = (tg & 3) ^ ((d >> 1) & 3);
    int4 val = *(const int4*)&vp[(long)d * 8192 + tg * 8];
    *(int4*)&vS[kk * 2048 + d * 32 + gp * 8] = val;
  }
  __syncthreads();

  u16* Pw = pS[wave];
  const float cscale = 0.18033688f;  // 64^-0.5 * log2(e)

#pragma unroll
  for (int sc = 0; sc < 2; ++sc) {
    const int q0 = wave * 32 + sc * 16;
    const int rt = wave * 2 + sc;
    const float* bT = &biasT[(long)(hi * 16 + rt) * 16 * 64 * 4];

    f32x4 sum4 = {0.f, 0.f, 0.f, 0.f};
    f32x4 o[4] = {};

#pragma unroll
    for (int m = 0; m < 4; ++m) {
      // S-stream: 4 jt -> exp2 -> P slots (kk = m*2, m*2+1)
#pragma unroll
      for (int j2 = 0; j2 < 4; ++j2) {
        const int jt = m * 4 + j2;
        bf16x8 a0 = *(const bf16x8*)&kS[(jt * 16 + l15) * 32 + gsw * 8];
        bf16x8 a1 = *(const bf16x8*)&kS[8192 + (jt * 16 + l15) * 32 + gsw * 8];
        f32x4 z = {0.f, 0.f, 0.f, 0.f};
        z = mfma16(a0, bq[sc][0], z);
        z = mfma16(a1, bq[sc][1], z);
        f32x4 bb = *(const f32x4*)&bT[(long)jt * 256 + lane * 4];
        f32x4 p;
#pragma unroll
        for (int r = 0; r < 4; ++r) {
          p[r] = __builtin_exp2f(z[r] * cscale + bb[r]);
          sum4[r] += p[r];
        }
        const int gp = ((jt & 1) * 2 + (quad >> 1)) ^ ((l15 >> 1) & 3);
        const int slot = (jt >> 1) & 1;
        uint2 w;
        w.x = pk2(p[0], p[1]);
        w.y = pk2(p[2], p[3]);
        *(uint2*)&Pw[slot * 512 + l15 * 32 + gp * 8 + (quad & 1) * 4] = w;
      }
      // PV for the 2 completed chunks (same-wave DS in-order; no barrier)
#pragma unroll
      for (int kk2 = 0; kk2 < 2; ++kk2) {
        const int kk = m * 2 + kk2;
        bf16x8 bp = *(const bf16x8*)&Pw[kk2 * 512 + l15 * 32 + gsw * 8];
#pragma unroll
        for (int dt = 0; dt < 4; ++dt) {
          bf16x8 av = *(const bf16x8*)&vS[kk * 2048 + (dt * 16 + l15) * 32 + gsw * 8];
          o[dt] = mfma16(av, bp, o[dt]);  // O^T[d][q]
        }
      }
    }

    // rowsum -> inv (q = l15 lives in-lane; 2 cross-quad shuffles)
    float sum = (sum4[0] + sum4[1]) + (sum4[2] + sum4[3]);
    sum += __shfl_xor(sum, 16);
    sum += __shfl_xor(sum, 32);
    const float inv = 1.0f / sum;

    // store: lane holds 4 consecutive d per dt at row n = grow+q0+l15 -> 8B packs
    const long rowoff = (grow + q0 + l15) * 512 + hi * 64 + quad * 4;
#pragma unroll
    for (int dt = 0; dt < 4; ++dt) {
      uint2 w;
      w.x = pk2(o[dt][0] * inv, o[dt][1] * inv);
      w.y = pk2(o[dt][2] * inv, o[dt][3] * inv);
      *(uint2*)&og[rowoff + dt * 16] = w;
    }
  }
}

// ---------- launcher ----------

extern "C" void kernel_launch(void* const* d_in, const int* in_sizes, int n_in,
                              void* d_out, int out_size, void* d_ws, size_t ws_size,
                              hipStream_t stream) {
  const float* x     = (const float*)d_in[0];
  const float* Wqkv  = (const float*)d_in[1];
  const float* bqkv  = (const float*)d_in[2];
  const float* Wproj = (const float*)d_in[3];
  const float* bproj = (const float*)d_in[4];
  const float* abias = (const float*)d_in[5];
  float* out = (float*)d_out;

  // workspace layout (bytes):
  //   qk natural bf16 [32768][1024]: 67,108,864
  //   v^T bf16 [2048][8192]:         33,554,432   (ends 100,663,296)
  //   WqkvT bf16: 1,572,864 | WprojT bf16: 524,288 | biasT fp32: 2,097,152
  //   x_bf16 [32768][512] (aliased as attn_out after qkv GEMM): 33,554,432
  char* ws = (char*)d_ws;
  u16*   qkp    = (u16*)(ws);
  u16*   vtb    = (u16*)(ws + 67108864L);
  u16*   wqkvT  = (u16*)(ws + 100663296L);
  u16*   wprojT = (u16*)(ws + 102236160L);
  float* biasTp = (float*)(ws + 102760448L);
  u16*   xbf    = (u16*)(ws + 104857600L);
  u16*   attnout = xbf;  // safe: x_bf16 dead after qkv GEMM (stream-ordered)

  prep_k<<<9344, 256, 0, stream>>>(x, xbf, Wqkv, wqkvT, Wproj, wprojT, abias, biasTp);
  qkv_gemm_k<<<768, 512, 0, stream>>>(xbf, wqkvT, bqkv, qkp, vtb);
  attn_win<<<1024, 512, 0, stream>>>(qkp, vtb, biasTp, attnout);
  proj_gemm_k<<<256, 512, 0, stream>>>(attnout, wprojT, bproj, out);
}

// Round 3
// 271.712 us; speedup vs baseline: 1.1056x; 1.0963x over previous
//
#include <hip/hip_runtime.h>

typedef unsigned short u16;
typedef unsigned int u32;
typedef __bf16 bf16x8 __attribute__((ext_vector_type(8)));
typedef float f32x4 __attribute__((ext_vector_type(4)));

// ---------- helpers ----------

__device__ __forceinline__ u16 f2bf(float f) {  // round-to-nearest-even fp32->bf16
  u32 u = __builtin_bit_cast(u32, f);
  u32 r = (u + 0x7fffu + ((u >> 16) & 1u)) >> 16;
  return (u16)r;
}
__device__ __forceinline__ u32 pk2(float a, float b) {
  return (u32)f2bf(a) | ((u32)f2bf(b) << 16);
}
__device__ __forceinline__ f32x4 mfma16(bf16x8 a, bf16x8 b, f32x4 c) {
  return __builtin_amdgcn_mfma_f32_16x16x32_bf16(a, b, c, 0, 0, 0);
}
// async global->LDS, 16B/lane; LDS dest = wave-uniform base + lane*16
__device__ __forceinline__ void glds16(const void* g, void* l) {
  typedef __attribute__((address_space(1))) void as1_void;
  typedef __attribute__((address_space(3))) void as3_void;
  __builtin_amdgcn_global_load_lds((as1_void*)g, (as3_void*)l, 16, 0, 0);
}

// ---------- kernel 1: fused prep ----------
// blocks [0,8192): x fp32->bf16 | [8192,8960): Wqkv^T | [8960,9216): Wproj^T
// [9216,9344): bias -> S^T D-layout table pre-scaled by log2(e)

__device__ __forceinline__ void transpose_body(const float* __restrict__ in,
                                               u16* __restrict__ out,
                                               int N, int n0, int k0) {
  __shared__ float t[32][33];
  int tx = threadIdx.x & 31, ty = threadIdx.x >> 5;  // 8 rows per pass
#pragma unroll
  for (int s = 0; s < 32; s += 8)
    t[ty + s][tx] = in[(long)(k0 + ty + s) * N + n0 + tx];
  __syncthreads();
#pragma unroll
  for (int s = 0; s < 32; s += 8)
    out[(long)(n0 + ty + s) * 512 + k0 + tx] = f2bf(t[tx][ty + s]);
}

__launch_bounds__(256)
__global__ void prep_k(const float* __restrict__ x, u16* __restrict__ xbf,
                       const float* __restrict__ Wqkv, u16* __restrict__ wqkvT,
                       const float* __restrict__ Wproj, u16* __restrict__ wprojT,
                       const float* __restrict__ bias, float* __restrict__ biasT) {
  const int id = blockIdx.x;
  if (id < 8192) {
    long i = ((long)id * 256 + threadIdx.x) * 8;
    float4 f0 = *(const float4*)(x + i);
    float4 f1 = *(const float4*)(x + i + 4);
    uint4 o;
    o.x = pk2(f0.x, f0.y);
    o.y = pk2(f0.z, f0.w);
    o.z = pk2(f1.x, f1.y);
    o.w = pk2(f1.z, f1.w);
    *(uint4*)(xbf + i) = o;
  } else if (id < 8960) {
    int bx = id - 8192;  // 768 = 48 x 16
    transpose_body(Wqkv, wqkvT, 1536, (bx % 48) * 32, (bx / 48) * 32);
  } else if (id < 9216) {
    int bx = id - 8960;  // 256 = 16 x 16
    transpose_body(Wproj, wprojT, 512, (bx & 15) * 32, (bx >> 4) * 32);
  } else {
    int hb = id - 9216;  // h*16 + rt
    int h = hb >> 4, rt = hb & 15;
    int lane = threadIdx.x & 63;
    int quad = lane >> 4, l15 = lane & 15;
    int jtg = threadIdx.x >> 6;  // 0..3
    const float L = 1.44269504f;
#pragma unroll
    for (int i = 0; i < 4; ++i) {
      int jt = jtg * 4 + i;
      float4 v = *(const float4*)&bias[((long)h * 256 + rt * 16 + l15) * 256 + jt * 16 + quad * 4];
      v.x *= L; v.y *= L; v.z *= L; v.w *= L;
      *(float4*)&biasT[(((long)hb * 16 + jt) * 64 + lane) * 4] = v;
    }
  }
}

// ---------- GEMM body: C = A(bf16 [M][512]) * Bt(bf16 [N][512])^T + bias ----------
// 128x128 tile, BK=64, 4 waves, 4x4 MFMA 16x16x32 tiles per wave.
// LDS chunk-major [c][row][32] with XOR swizzle (pos = g ^ ((row>>1)&3)).
// Round-0 verified structure (75.6 us, 681 TF, MfmaUtil 28%). Two deep-pipeline
// rewrites (1-block/CU 256² 8-wave, rounds 1-2) measured 95 and 123 us — the
// lockstep barrier schedule kills the implicit multi-block overlap (m114/m228d).
// Do NOT re-pipeline this at 128²; single-buffered + ~2-3 resident blocks wins.
// EPI=0: q/k cols -> natural [32768][1024] bf16; v cols -> v^T [(b*8+h)*64+d][8192] bf16.
// EPI=1: fp32 row-major [32768][512] output (d_out).

template <int EPI>
__device__ __forceinline__ void gemm_body(const u16* __restrict__ A, const u16* __restrict__ Bt,
                                          const float* __restrict__ bias,
                                          u16* __restrict__ oqk, u16* __restrict__ ovt,
                                          float* __restrict__ ofp,
                                          long arow0, long brow0) {
  constexpr int K = 512;
  __shared__ u16 Asm[8192];
  __shared__ u16 Bsm[8192];

  const int tid = threadIdx.x;
  const int wave = tid >> 6, lane = tid & 63;
  const int quad = lane >> 4, l15 = lane & 15;
  const int wm = wave >> 1, wn = wave & 1;
  const int gsw = quad ^ ((l15 >> 1) & 3);

  f32x4 acc[4][4] = {};

  for (int k0 = 0; k0 < K; k0 += 64) {
#pragma unroll
    for (int rd = 0; rd < 4; ++rd) {
      int flat = rd * 256 + tid;  // 16B-block index 0..1023
      int c = flat >> 9, row = (flat >> 2) & 127, gp = flat & 3;
      int g = gp ^ ((row >> 1) & 3);
      const long koff = k0 + c * 32 + g * 8;
      glds16(A + (arow0 + row) * K + koff, &Asm[(rd * 256 + wave * 64) * 8]);
      glds16(Bt + (brow0 + row) * K + koff, &Bsm[(rd * 256 + wave * 64) * 8]);
    }
    __syncthreads();
#pragma unroll
    for (int c = 0; c < 2; ++c) {
      bf16x8 af[4], bfr[4];
#pragma unroll
      for (int i = 0; i < 4; ++i)
        af[i] = *(const bf16x8*)&Asm[c * 4096 + (wm * 64 + i * 16 + l15) * 32 + gsw * 8];
#pragma unroll
      for (int j = 0; j < 4; ++j)
        bfr[j] = *(const bf16x8*)&Bsm[c * 4096 + (wn * 64 + j * 16 + l15) * 32 + gsw * 8];
#pragma unroll
      for (int i = 0; i < 4; ++i)
#pragma unroll
        for (int j = 0; j < 4; ++j)
          acc[i][j] = mfma16(af[i], bfr[j], acc[i][j]);
    }
    __syncthreads();
  }

  // epilogue: D-layout row = quad*4 + r, col = l15
#pragma unroll
  for (int j = 0; j < 4; ++j) {
    const int C = (int)brow0 + wn * 64 + j * 16 + l15;
    const float bc = bias[C];
#pragma unroll
    for (int i = 0; i < 4; ++i) {
      const long R0 = arow0 + wm * 64 + i * 16 + quad * 4;
      float v4[4];
#pragma unroll
      for (int r = 0; r < 4; ++r) v4[r] = acc[i][j][r] + bc;
      if constexpr (EPI == 0) {
        if (C < 1024) {  // q/k: natural rows (wave-uniform branch)
#pragma unroll
          for (int r = 0; r < 4; ++r) oqk[(R0 + r) * 1024 + C] = f2bf(v4[r]);
        } else {         // v: transposed, packed 8B along n
          const int hc = (C >> 6) & 7, dc = C & 63;
          const int b = (int)(R0 >> 13), n0 = (int)(R0 & 8191);
          uint2 w;
          w.x = pk2(v4[0], v4[1]);
          w.y = pk2(v4[2], v4[3]);
          *(uint2*)&ovt[((long)(b * 8 + hc) * 64 + dc) * 8192 + n0] = w;
        }
      } else {
#pragma unroll
        for (int r = 0; r < 4; ++r) ofp[(R0 + r) * 512 + C] = v4[r];
      }
    }
  }
}

// XCD-aware swizzle (heuristic, perf-only): xcd = bid % 8 owns a contiguous band of
// 32 M-tiles; N fastest within the band -> each A-tile lives in exactly one XCD L2,
// B stays resident.

__launch_bounds__(256)
__global__ void qkv_gemm_k(const u16* __restrict__ A, const u16* __restrict__ Bt,
                           const float* __restrict__ bias,
                           u16* __restrict__ oqk, u16* __restrict__ ovt) {
  int bid = blockIdx.x;               // 3072 = 8 xcd * 32 mt * 12 nt
  int xcd = bid & 7, i = bid >> 3;
  int nt = i % 12, mtl = i / 12;
  gemm_body<0>(A, Bt, bias, oqk, ovt, nullptr,
               (long)(xcd * 32 + mtl) * 128, (long)nt * 128);
}

__launch_bounds__(256)
__global__ void proj_gemm_k(const u16* __restrict__ A, const u16* __restrict__ Bt,
                            const float* __restrict__ bias, float* __restrict__ ofp) {
  int bid = blockIdx.x;               // 1024 = 8 xcd * 32 mt * 4 nt
  int xcd = bid & 7, i = bid >> 3;
  int nt = i & 3, mtl = i >> 2;
  gemm_body<1>(A, Bt, bias, nullptr, nullptr, ofp,
               (long)(xcd * 32 + mtl) * 128, (long)nt * 128);
}

// ---------- attention: one 512-thread block per (b,h,window) ----------
// S^T = K Q^T formulation, streaming no-max softmax (scores bounded ~|2|).
// XCD swizzle clusters the 8 heads of a window on one XCD (q/k rows share lines).
// q frags hoisted above the barrier to overlap staging.
// T5: s_setprio(1) around MFMA clusters — independent 1-wave-phase blocks, the
// regime where m191 measured +4-7% (GEMM's lockstep waves get none: m190).

__launch_bounds__(512, 4)
__global__ void attn_win(const u16* __restrict__ qk, const u16* __restrict__ vtb,
                         const float* __restrict__ biasT, u16* __restrict__ og) {
  __shared__ __align__(16) u16 kS[16384];    // [c][256 t][32], pos = g^((t>>1)&3)   32 KB
  __shared__ __align__(16) u16 vS[16384];    // [kk 8][64 d][32], pos = g^((d>>1)&3) 32 KB
  __shared__ __align__(16) u16 pS[8][1024];  // per-wave 2 slots x [16 q][32 t]      16 KB

  const int tid = threadIdx.x;
  const int wave = tid >> 6, lane = tid & 63;
  const int quad = lane >> 4, l15 = lane & 15;
  const int gsw = quad ^ ((l15 >> 1) & 3);

  // swizzle: 1024 = 8 xcd * 8 h * 16 wl ; window = xcd*16 + wl  (all 8 heads co-XCD)
  const int wi = blockIdx.x;
  const int xcd = wi & 7, hi = (wi >> 3) & 7, wl = wi >> 6;
  const int win = xcd * 16 + wl;             // [0,128)
  const int nwi = win & 31, bi = win >> 5;
  const long grow = (long)bi * 8192 + nwi * 256;
  const u16* qp = qk + grow * 1024 + hi * 64;
  const u16* kp = qp + 512;
  const u16* vp = vtb + (long)(bi * 8 + hi) * 64 * 8192 + nwi * 256;  // [d][256]

  // q B-frags for both sub-chunks, issued before the barrier (overlap staging)
  bf16x8 bq[2][2];
#pragma unroll
  for (int sc = 0; sc < 2; ++sc) {
    const int q0 = wave * 32 + sc * 16;
    bq[sc][0] = *(const bf16x8*)&qp[(long)(q0 + l15) * 1024 + quad * 8];
    bq[sc][1] = *(const bf16x8*)&qp[(long)(q0 + l15) * 1024 + 32 + quad * 8];
  }

  // stage k rows -> chunk-major swizzled LDS (512 threads: 4 iters)
#pragma unroll
  for (int it = 0; it < 4; ++it) {
    int flat = it * 512 + tid;
    int t = flat >> 3, dg = flat & 7;
    int c = dg >> 2, gp = (dg & 3) ^ ((t >> 1) & 3);
    int4 val = *(const int4*)&kp[(long)t * 1024 + dg * 8];
    *(int4*)&kS[c * 8192 + t * 32 + gp * 8] = val;
  }
  // stage v^T rows -> chunk-major swizzled LDS (coalesced 512B/d-row)
#pragma unroll
  for (int it = 0; it < 4; ++it) {
    int flat = it * 512 + tid;
    int d = flat >> 5, tg = flat & 31;
    int kk = tg >> 2, gp = (tg & 3) ^ ((d >> 1) & 3);
    int4 val = *(const int4*)&vp[(long)d * 8192 + tg * 8];
    *(int4*)&vS[kk * 2048 + d * 32 + gp * 8] = val;
  }
  __syncthreads();

  u16* Pw = pS[wave];
  const float cscale = 0.18033688f;  // 64^-0.5 * log2(e)

#pragma unroll
  for (int sc = 0; sc < 2; ++sc) {
    const int q0 = wave * 32 + sc * 16;
    const int rt = wave * 2 + sc;
    const float* bT = &biasT[(long)(hi * 16 + rt) * 16 * 64 * 4];

    f32x4 sum4 = {0.f, 0.f, 0.f, 0.f};
    f32x4 o[4] = {};

#pragma unroll
    for (int m = 0; m < 4; ++m) {
      // S-stream: 4 jt -> exp2 -> P slots (kk = m*2, m*2+1)
#pragma unroll
      for (int j2 = 0; j2 < 4; ++j2) {
        const int jt = m * 4 + j2;
        bf16x8 a0 = *(const bf16x8*)&kS[(jt * 16 + l15) * 32 + gsw * 8];
        bf16x8 a1 = *(const bf16x8*)&kS[8192 + (jt * 16 + l15) * 32 + gsw * 8];
        f32x4 z = {0.f, 0.f, 0.f, 0.f};
        __builtin_amdgcn_s_setprio(1);
        z = mfma16(a0, bq[sc][0], z);
        z = mfma16(a1, bq[sc][1], z);
        __builtin_amdgcn_s_setprio(0);
        f32x4 bb = *(const f32x4*)&bT[(long)jt * 256 + lane * 4];
        f32x4 p;
#pragma unroll
        for (int r = 0; r < 4; ++r) {
          p[r] = __builtin_exp2f(z[r] * cscale + bb[r]);
          sum4[r] += p[r];
        }
        const int gp = ((jt & 1) * 2 + (quad >> 1)) ^ ((l15 >> 1) & 3);
        const int slot = (jt >> 1) & 1;
        uint2 w;
        w.x = pk2(p[0], p[1]);
        w.y = pk2(p[2], p[3]);
        *(uint2*)&Pw[slot * 512 + l15 * 32 + gp * 8 + (quad & 1) * 4] = w;
      }
      // PV for the 2 completed chunks (same-wave DS in-order; no barrier)
#pragma unroll
      for (int kk2 = 0; kk2 < 2; ++kk2) {
        const int kk = m * 2 + kk2;
        bf16x8 bp = *(const bf16x8*)&Pw[kk2 * 512 + l15 * 32 + gsw * 8];
        __builtin_amdgcn_s_setprio(1);
#pragma unroll
        for (int dt = 0; dt < 4; ++dt) {
          bf16x8 av = *(const bf16x8*)&vS[kk * 2048 + (dt * 16 + l15) * 32 + gsw * 8];
          o[dt] = mfma16(av, bp, o[dt]);  // O^T[d][q]
        }
        __builtin_amdgcn_s_setprio(0);
      }
    }

    // rowsum -> inv (q = l15 lives in-lane; 2 cross-quad shuffles)
    float sum = (sum4[0] + sum4[1]) + (sum4[2] + sum4[3]);
    sum += __shfl_xor(sum, 16);
    sum += __shfl_xor(sum, 32);
    const float inv = 1.0f / sum;

    // store: lane holds 4 consecutive d per dt at row n = grow+q0+l15 -> 8B packs
    const long rowoff = (grow + q0 + l15) * 512 + hi * 64 + quad * 4;
#pragma unroll
    for (int dt = 0; dt < 4; ++dt) {
      uint2 w;
      w.x = pk2(o[dt][0] * inv, o[dt][1] * inv);
      w.y = pk2(o[dt][2] * inv, o[dt][3] * inv);
      *(uint2*)&og[rowoff + dt * 16] = w;
    }
  }
}

// ---------- launcher ----------

extern "C" void kernel_launch(void* const* d_in, const int* in_sizes, int n_in,
                              void* d_out, int out_size, void* d_ws, size_t ws_size,
                              hipStream_t stream) {
  const float* x     = (const float*)d_in[0];
  const float* Wqkv  = (const float*)d_in[1];
  const float* bqkv  = (const float*)d_in[2];
  const float* Wproj = (const float*)d_in[3];
  const float* bproj = (const float*)d_in[4];
  const float* abias = (const float*)d_in[5];
  float* out = (float*)d_out;

  // workspace layout (bytes):
  //   qk natural bf16 [32768][1024]: 67,108,864
  //   v^T bf16 [2048][8192]:         33,554,432   (ends 100,663,296)
  //   WqkvT bf16: 1,572,864 | WprojT bf16: 524,288 | biasT fp32: 2,097,152
  //   x_bf16 [32768][512] (aliased as attn_out after qkv GEMM): 33,554,432
  char* ws = (char*)d_ws;
  u16*   qkp    = (u16*)(ws);
  u16*   vtb    = (u16*)(ws + 67108864L);
  u16*   wqkvT  = (u16*)(ws + 100663296L);
  u16*   wprojT = (u16*)(ws + 102236160L);
  float* biasTp = (float*)(ws + 102760448L);
  u16*   xbf    = (u16*)(ws + 104857600L);
  u16*   attnout = xbf;  // safe: x_bf16 dead after qkv GEMM (stream-ordered)

  prep_k<<<9344, 256, 0, stream>>>(x, xbf, Wqkv, wqkvT, Wproj, wprojT, abias, biasTp);
  qkv_gemm_k<<<3072, 256, 0, stream>>>(xbf, wqkvT, bqkv, qkp, vtb);
  attn_win<<<1024, 512, 0, stream>>>(qkp, vtb, biasTp, attnout);
  proj_gemm_k<<<1024, 256, 0, stream>>>(attnout, wprojT, bproj, out);
}